// Round 16
// baseline (116.256 us; speedup 1.0000x reference)
//
#include <hip/hip_runtime.h>
#include <hip/hip_fp16.h>

#define NEG 0.2f
#define BNEPS 1e-5f
#define NPART 256

typedef _Float16 f16x8 __attribute__((ext_vector_type(8)));
typedef float f32x4 __attribute__((ext_vector_type(4)));

// ---------------- Fused persistent GEMM1 (MFMA) + edge partition ----------------
// blocks [0, gemm_blocks): persistent — stage W1 once, loop over 64-row tiles.
// blocks [gemm_blocks, ...): partition edges into 256 dst-range buckets.
__global__ __launch_bounds__(256) void gemm1_part_kernel(
    const float* __restrict__ x, const float* __restrict__ W1,
    const float* __restrict__ asrc, const float* __restrict__ adst,
    __half2* __restrict__ h1h, float* __restrict__ ssrc1, float* __restrict__ sdst1,
    int n, int nTiles, int gemm_blocks,
    const int* __restrict__ srcp, const int* __restrict__ dstp, int E, int Etot, int chunk,
    int2* __restrict__ pairs, int pcap, int* __restrict__ pcur)
{
    __shared__ _Float16 Ws[128 * 136];
    __shared__ _Float16 Xs[4 * 16 * 136];
    int tid = threadIdx.x, lane = tid & 63, wv = tid >> 6;

    if (blockIdx.x >= gemm_blocks) {
        int* lcnt = (int*)Ws;
        int* lbase = (int*)Ws + 256;
        const int PER = 8;
        int t0 = (blockIdx.x - gemm_blocks) * 256 * PER;
        lcnt[tid] = 0;
        __syncthreads();
        int myd[PER], mys[PER], myp[PER];
#pragma unroll
        for (int j = 0; j < PER; ++j) {
            int i = t0 + j * 256 + tid;
            if (i < Etot) {
                int s, d;
                if (i < E) { s = srcp[i]; d = dstp[i]; } else { s = i - E; d = i - E; }
                myd[j] = d; mys[j] = s; myp[j] = d / chunk;
                atomicAdd(&lcnt[myp[j]], 1);
            } else myp[j] = -1;
        }
        __syncthreads();
        lbase[tid] = atomicAdd(&pcur[tid], lcnt[tid]);
        lcnt[tid] = 0;
        __syncthreads();
#pragma unroll
        for (int j = 0; j < PER; ++j) {
            if (myp[j] >= 0) {
                int r = atomicAdd(&lcnt[myp[j]], 1);
                int pos = lbase[myp[j]] + r;
                if (pos < pcap) pairs[(size_t)myp[j] * pcap + pos] = make_int2(myd[j], mys[j]);
            }
        }
        return;
    }

    // ---- persistent gemm1 body ----
    // stage W1 once (coalesced), one barrier; Xs is wave-private -> loop body sync-free
#pragma unroll
    for (int it = 0; it < 16; ++it) {
        int idx = it * 256 + tid;          // 128 rows x 32 f4
        int c = idx >> 5, kq = idx & 31;
        float4 v = ((const float4*)W1)[idx];
        _Float16* dst = &Ws[c * 136 + kq * 4];
        dst[0] = (_Float16)v.x; dst[1] = (_Float16)v.y;
        dst[2] = (_Float16)v.z; dst[3] = (_Float16)v.w;
    }
    __syncthreads();

    int q = lane & 15, kg = lane >> 4;
    float as_reg[8], ad_reg[8];
#pragma unroll
    for (int t = 0; t < 8; ++t) { as_reg[t] = asrc[t * 16 + q]; ad_reg[t] = adst[t * 16 + q]; }

    for (int tile = blockIdx.x; tile < nTiles; tile += gemm_blocks) {
        int rbase = tile * 64 + wv * 16;
        // stage 16 x-rows (wave-private region of Xs)
#pragma unroll
        for (int it = 0; it < 8; ++it) {
            int idx = it * 64 + lane;      // 16 rows x 32 f4
            int r = idx >> 5, kq = idx & 31;
            int grow = rbase + r;
            float4 v = make_float4(0.f, 0.f, 0.f, 0.f);
            if (grow < n) v = ((const float4*)(x + (size_t)grow * 128))[kq];
            _Float16* dst = &Xs[(wv * 16 + r) * 136 + kq * 4];
            dst[0] = (_Float16)v.x; dst[1] = (_Float16)v.y;
            dst[2] = (_Float16)v.z; dst[3] = (_Float16)v.w;
        }

        f32x4 acc[8];
#pragma unroll
        for (int t = 0; t < 8; ++t) acc[t] = (f32x4){0.f, 0.f, 0.f, 0.f};
#pragma unroll
        for (int kt = 0; kt < 4; ++kt) {
            f16x8 a = *(const f16x8*)&Xs[(wv * 16 + q) * 136 + kt * 32 + kg * 8];
#pragma unroll
            for (int t = 0; t < 8; ++t) {
                f16x8 b = *(const f16x8*)&Ws[(t * 16 + q) * 136 + kt * 32 + kg * 8];
                acc[t] = __builtin_amdgcn_mfma_f32_16x16x32_f16(a, b, acc[t], 0, 0, 0);
            }
        }

        float sp[4][4], sd[4][4];
#pragma unroll
        for (int i = 0; i < 4; ++i)
#pragma unroll
            for (int h = 0; h < 4; ++h) { sp[i][h] = 0.f; sd[i][h] = 0.f; }
#pragma unroll
        for (int t = 0; t < 8; ++t) {
            int h = t >> 1;
#pragma unroll
            for (int i = 0; i < 4; ++i) {
                sp[i][h] += acc[t][i] * as_reg[t];
                sd[i][h] += acc[t][i] * ad_reg[t];
            }
        }
#pragma unroll
        for (int m = 1; m <= 8; m <<= 1) {
#pragma unroll
            for (int i = 0; i < 4; ++i)
#pragma unroll
                for (int h = 0; h < 4; ++h) {
                    sp[i][h] += __shfl_xor(sp[i][h], m, 64);
                    sd[i][h] += __shfl_xor(sd[i][h], m, 64);
                }
        }
        if (q == 0) {
#pragma unroll
            for (int i = 0; i < 4; ++i) {
                int row = rbase + kg * 4 + i;
                if (row < n) {
#pragma unroll
                    for (int h = 0; h < 4; ++h) {
                        ssrc1[row * 4 + h] = sp[i][h];
                        sdst1[row * 4 + h] = sd[i][h];
                    }
                }
            }
        }

        // transpose D fragments into wave-private Xs, then coalesced fp16 store
#pragma unroll
        for (int t = 0; t < 8; ++t)
#pragma unroll
            for (int i = 0; i < 4; ++i)
                Xs[(wv * 16 + kg * 4 + i) * 136 + t * 16 + q] = (_Float16)acc[t][i];
#pragma unroll
        for (int it = 0; it < 4; ++it) {
            int idx = it * 64 + lane;
            int r = idx >> 4, kq = idx & 15;
            int grow = rbase + r;
            if (grow < n)
                ((float4*)((__half*)h1h + (size_t)grow * 128))[kq] =
                    *(const float4*)&Xs[(wv * 16 + r) * 136 + kq * 8];
        }
    }
}

// ---------------- CSR pass 2: 512 threads per partition ----------------
__global__ __launch_bounds__(512) void csr_kernel(
    const int2* __restrict__ pairs, int pcap, const int* __restrict__ pcnt,
    int* __restrict__ rowptr, int* __restrict__ col, int N, int chunk, int Etot)
{
    __shared__ int ldeg[NPART];
    __shared__ int wtmp[8];
    __shared__ int sh_pbase;
    int p = blockIdx.x;
    int lo = p * chunk;
    int hi = min(lo + chunk, N);
    int len = max(hi - lo, 0);
    int tid = threadIdx.x;
    int lane = tid & 63, wv = tid >> 6;

    if (tid < NPART) {
        int v = pcnt[tid];
        int inc = v;
#pragma unroll
        for (int m = 1; m < 64; m <<= 1) {
            int t = __shfl_up(inc, m, 64);
            if (lane >= m) inc += t;
        }
        if (lane == 63) wtmp[wv] = inc;
        ldeg[tid] = 0;
        __syncthreads();
        int woff = 0;
        for (int w = 0; w < wv; ++w) woff += wtmp[w];
        if (tid == p) sh_pbase = inc - v + woff;
    } else {
        __syncthreads();
    }
    __syncthreads();

    int cnt = min(pcnt[p], pcap);
    const int2* pp = pairs + (size_t)p * pcap;
    for (int i = tid; i < cnt; i += 512) {
        atomicAdd(&ldeg[pp[i].x - lo], 1);
    }
    __syncthreads();

    int excl = 0;
    if (tid < NPART) {
        int v = (tid < len) ? ldeg[tid] : 0;
        int inc = v;
#pragma unroll
        for (int m = 1; m < 64; m <<= 1) {
            int t = __shfl_up(inc, m, 64);
            if (lane >= m) inc += t;
        }
        if (lane == 63) wtmp[wv] = inc;
        __syncthreads();
        int woff = 0;
        for (int w = 0; w < wv; ++w) woff += wtmp[w];
        excl = inc - v + woff;
    } else {
        __syncthreads();
    }
    int base = sh_pbase;
    __syncthreads();
    if (tid < len) {
        rowptr[lo + tid] = base + excl;
        ldeg[tid] = base + excl;
    }
    if (p == NPART - 1 && tid == 0) rowptr[N] = Etot;
    __syncthreads();

    for (int i = tid; i < cnt; i += 512) {
        int2 e = pp[i];
        int pos = atomicAdd(&ldeg[e.x - lo], 1);
        col[pos] = e.y;
    }
}

// ---------------- GAT layer-1: 4-streams x 16-lane aggregate + bias + BN1 + ELU (fp16 out) -------
__global__ __launch_bounds__(256) void agg1_kernel(
    const __half2* __restrict__ h1h, const float* __restrict__ ssrc1, const float* __restrict__ sdst1,
    const int* __restrict__ rowptr, const int* __restrict__ col,
    const float* __restrict__ b1, const float* __restrict__ g1, const float* __restrict__ be1,
    const float* __restrict__ mu1, const float* __restrict__ var1,
    _Float16* __restrict__ hbn1h, int n)
{
    int node = blockIdx.x * 4 + (threadIdx.x >> 6);
    int lane = threadIdx.x & 63;
    if (node >= n) return;
    int start = rowptr[node], end = rowptr[node + 1];
    int g = lane >> 4;          // edge stream (0..3)
    int q = lane & 15;          // channel quad: ch 8q..8q+7
    int hd = q >> 2;            // head of my 8 channels
    float sdh = sdst1[node * 4 + hd];

    float acc[8] = {0.f, 0.f, 0.f, 0.f, 0.f, 0.f, 0.f, 0.f};
    float dn = 0.f;
#pragma unroll 2
    for (int j = start + g; j < end; j += 4) {
        int s = col[j];
        float e = ssrc1[s * 4 + hd] + sdh;
        e = (e > 0.f) ? e : NEG * e;
        float w = __expf(e);
        dn += w;
        float4 hv = *(const float4*)((const char*)(h1h + (size_t)s * 64) + 16 * q);
        const __half2* hp = (const __half2*)&hv;
#pragma unroll
        for (int t = 0; t < 4; ++t) {
            float2 f = __half22float2(hp[t]);
            acc[2 * t]     += w * f.x;
            acc[2 * t + 1] += w * f.y;
        }
    }
#pragma unroll
    for (int m = 16; m <= 32; m <<= 1) {
        dn += __shfl_xor(dn, m, 64);
#pragma unroll
        for (int t = 0; t < 8; ++t) acc[t] += __shfl_xor(acc[t], m, 64);
    }
    if (lane < 16) {
        float iv = 1.f / dn;
        int c = 8 * q;
        float outv[8];
#pragma unroll
        for (int tt = 0; tt < 2; ++tt) {
            float4 bv = *(const float4*)(b1 + c + 4 * tt);
            float4 gv = *(const float4*)(g1 + c + 4 * tt);
            float4 ev = *(const float4*)(be1 + c + 4 * tt);
            float4 mv = *(const float4*)(mu1 + c + 4 * tt);
            float4 vv = *(const float4*)(var1 + c + 4 * tt);
            const float* bp = (const float*)&bv;
            const float* gp = (const float*)&gv;
            const float* ep = (const float*)&ev;
            const float* mp = (const float*)&mv;
            const float* vp = (const float*)&vv;
#pragma unroll
            for (int t = 0; t < 4; ++t) {
                float u = acc[4 * tt + t] * iv + bp[t];
                u = (u - mp[t]) * (gp[t] * rsqrtf(vp[t] + BNEPS)) + ep[t];
                outv[4 * tt + t] = (u > 0.f) ? u : (__expf(u) - 1.f);
            }
        }
        f16x8 ov;
#pragma unroll
        for (int t = 0; t < 8; ++t) ov[t] = (_Float16)outv[t];
        *(f16x8*)&hbn1h[(size_t)node * 128 + c] = ov;
    }
}

// ---------------- GEMM2 (MFMA): h2 = hbn1 @ W2^T [N,32] fp16 + s_src2/s_dst2 [N] ----------------
__global__ __launch_bounds__(256) void gemm2_kernel(
    const _Float16* __restrict__ hbn1h, const float* __restrict__ W2,
    const float* __restrict__ asrc2, const float* __restrict__ adst2,
    __half2* __restrict__ h2h, float* __restrict__ ssrc2, float* __restrict__ sdst2, int n)
{
    __shared__ _Float16 Ws[32 * 136];
    int tid = threadIdx.x, lane = tid & 63, wv = tid >> 6;
#pragma unroll
    for (int it = 0; it < 4; ++it) {
        int idx = it * 256 + tid;
        int c = idx >> 5, kq = idx & 31;
        float4 v = ((const float4*)W2)[idx];
        _Float16* dst = &Ws[c * 136 + kq * 4];
        dst[0] = (_Float16)v.x; dst[1] = (_Float16)v.y;
        dst[2] = (_Float16)v.z; dst[3] = (_Float16)v.w;
    }
    __syncthreads();

    int rbase = blockIdx.x * 64 + wv * 16;
    int q = lane & 15, kg = lane >> 4;
    int arow = min(rbase + q, n - 1);
    f32x4 acc[2];
    acc[0] = (f32x4){0.f, 0.f, 0.f, 0.f};
    acc[1] = (f32x4){0.f, 0.f, 0.f, 0.f};
#pragma unroll
    for (int kt = 0; kt < 4; ++kt) {
        f16x8 a = *(const f16x8*)&hbn1h[(size_t)arow * 128 + kt * 32 + kg * 8];
#pragma unroll
        for (int t = 0; t < 2; ++t) {
            f16x8 b = *(const f16x8*)&Ws[(t * 16 + q) * 136 + kt * 32 + kg * 8];
            acc[t] = __builtin_amdgcn_mfma_f32_16x16x32_f16(a, b, acc[t], 0, 0, 0);
        }
    }

    float sp[4] = {0.f, 0.f, 0.f, 0.f}, sd[4] = {0.f, 0.f, 0.f, 0.f};
#pragma unroll
    for (int t = 0; t < 2; ++t) {
        float as = asrc2[t * 16 + q], ad = adst2[t * 16 + q];
#pragma unroll
        for (int i = 0; i < 4; ++i) {
            sp[i] += acc[t][i] * as;
            sd[i] += acc[t][i] * ad;
        }
    }
#pragma unroll
    for (int m = 1; m <= 8; m <<= 1) {
#pragma unroll
        for (int i = 0; i < 4; ++i) {
            sp[i] += __shfl_xor(sp[i], m, 64);
            sd[i] += __shfl_xor(sd[i], m, 64);
        }
    }
    if (q == 0) {
#pragma unroll
        for (int i = 0; i < 4; ++i) {
            int row = rbase + kg * 4 + i;
            if (row < n) { ssrc2[row] = sp[i]; sdst2[row] = sd[i]; }
        }
    }
#pragma unroll
    for (int t = 0; t < 2; ++t) {
#pragma unroll
        for (int i = 0; i < 4; ++i) {
            float v = acc[t][i];
            float vn = __shfl_xor(v, 1, 64);
            if ((q & 1) == 0) {
                int row = rbase + kg * 4 + i;
                if (row < n)
                    h2h[(size_t)row * 16 + t * 8 + (q >> 1)] = __floats2half2_rn(v, vn);
            }
        }
    }
}

// ---------------- GAT layer-2: 8-streams x 2 nodes/wave aggregate + BN2 + ELU + classifier -------
__global__ __launch_bounds__(256) void agg2_kernel(
    const __half2* __restrict__ h2h, const float* __restrict__ ssrc2, const float* __restrict__ sdst2,
    const int* __restrict__ rowptr, const int* __restrict__ col,
    const float* __restrict__ b2, const float* __restrict__ g2, const float* __restrict__ be2,
    const float* __restrict__ mu2, const float* __restrict__ var2,
    const float* __restrict__ Wc, const float* __restrict__ bc,
    float* __restrict__ out, int n)
{
    int tid = threadIdx.x;
    int lane = tid & 63;
    int node = blockIdx.x * 8 + (tid >> 6) * 2 + (lane >> 5);
    if (node >= n) return;
    int g = (lane >> 2) & 7;
    int cq = lane & 3;
    int start = rowptr[node], end = rowptr[node + 1];
    float sd = sdst2[node];

    float acc[8] = {0.f, 0.f, 0.f, 0.f, 0.f, 0.f, 0.f, 0.f};
    float dn = 0.f;
    for (int j = start + g; j < end; j += 8) {
        int s = col[j];
        float e = ssrc2[s] + sd;
        e = (e > 0.f) ? e : NEG * e;
        float w = __expf(e);
        dn += w;
        float4 hv = *(const float4*)((const char*)(h2h + (size_t)s * 16) + 16 * cq);
        const __half2* hp = (const __half2*)&hv;
#pragma unroll
        for (int t = 0; t < 4; ++t) {
            float2 f = __half22float2(hp[t]);
            acc[2 * t]     += w * f.x;
            acc[2 * t + 1] += w * f.y;
        }
    }
#pragma unroll
    for (int m = 4; m <= 16; m <<= 1) {
        dn += __shfl_xor(dn, m, 64);
#pragma unroll
        for (int t = 0; t < 8; ++t) acc[t] += __shfl_xor(acc[t], m, 64);
    }
    float iv = 1.f / dn;
    int c = 8 * cq;
    float4 b0 = *(const float4*)(b2 + c),   b4 = *(const float4*)(b2 + c + 4);
    float4 g0 = *(const float4*)(g2 + c),   g4 = *(const float4*)(g2 + c + 4);
    float4 e0 = *(const float4*)(be2 + c),  e4 = *(const float4*)(be2 + c + 4);
    float4 m0 = *(const float4*)(mu2 + c),  m4 = *(const float4*)(mu2 + c + 4);
    float4 v0 = *(const float4*)(var2 + c), v4 = *(const float4*)(var2 + c + 4);
    const float* bp = (const float*)&b0;  const float* bp4 = (const float*)&b4;
    const float* gp = (const float*)&g0;  const float* gp4 = (const float*)&g4;
    const float* ep = (const float*)&e0;  const float* ep4 = (const float*)&e4;
    const float* mp = (const float*)&m0;  const float* mp4 = (const float*)&m4;
    const float* vp = (const float*)&v0;  const float* vp4 = (const float*)&v4;
    float v[8];
#pragma unroll
    for (int t = 0; t < 4; ++t) {
        float u = acc[t] * iv + bp[t];
        u = (u - mp[t]) * (gp[t] * rsqrtf(vp[t] + BNEPS)) + ep[t];
        v[t] = (u > 0.f) ? u : (__expf(u) - 1.f);
    }
#pragma unroll
    for (int t = 0; t < 4; ++t) {
        float u = acc[4 + t] * iv + bp4[t];
        u = (u - mp4[t]) * (gp4[t] * rsqrtf(vp4[t] + BNEPS)) + ep4[t];
        v[4 + t] = (u > 0.f) ? u : (__expf(u) - 1.f);
    }
#pragma unroll
    for (int rr = 0; rr < 2; ++rr) {
        int o = g + 8 * rr;
        float t = 0.f;
        if (o < 10) {
            const float* wc = Wc + o * 32 + c;
#pragma unroll
            for (int k = 0; k < 8; ++k) t += v[k] * wc[k];
        }
        t += __shfl_xor(t, 1, 64);
        t += __shfl_xor(t, 2, 64);
        if (cq == 0 && o < 10) out[(size_t)node * 10 + o] = t + bc[o];
    }
}

extern "C" void kernel_launch(void* const* d_in, const int* in_sizes, int n_in,
                              void* d_out, int out_size, void* d_ws, size_t ws_size,
                              hipStream_t stream)
{
    const float* x     = (const float*)d_in[0];
    const int*   ei    = (const int*)d_in[1];
    const float* W1    = (const float*)d_in[2];
    const float* asrc1 = (const float*)d_in[3];
    const float* adst1 = (const float*)d_in[4];
    const float* b1    = (const float*)d_in[5];
    const float* g1    = (const float*)d_in[6];
    const float* be1   = (const float*)d_in[7];
    const float* mu1   = (const float*)d_in[8];
    const float* var1  = (const float*)d_in[9];
    const float* W2    = (const float*)d_in[10];
    const float* asrc2 = (const float*)d_in[11];
    const float* adst2 = (const float*)d_in[12];
    const float* b2    = (const float*)d_in[13];
    const float* g2    = (const float*)d_in[14];
    const float* be2   = (const float*)d_in[15];
    const float* mu2   = (const float*)d_in[16];
    const float* var2  = (const float*)d_in[17];
    const float* Wc    = (const float*)d_in[18];
    const float* bc    = (const float*)d_in[19];

    int N_ = in_sizes[0] / 128;
    int E_ = in_sizes[1] / 2;
    int Etot = E_ + N_;
    const int* srcp = ei;
    const int* dstp = ei + E_;
    int chunk = (N_ + NPART - 1) / NPART;
    int pcap = Etot / NPART + 1024;

    char* ws = (char*)d_ws;
    size_t off = 0;
    auto alloc = [&](size_t bytes) -> char* {
        char* p = ws + off;
        off += (bytes + 255) & ~(size_t)255;
        return p;
    };
    __half2*   h1h   = (__half2*)alloc((size_t)N_ * 64 * 4);
    _Float16*  hbn1h = (_Float16*)alloc((size_t)N_ * 128 * 2);
    __half2*   h2h   = (__half2*)alloc((size_t)N_ * 16 * 4);
    float*     ssrc1 = (float*)alloc((size_t)N_ * 4 * 4);
    float*     sdst1 = (float*)alloc((size_t)N_ * 4 * 4);
    float*     ssrc2 = (float*)alloc((size_t)N_ * 4);
    float*     sdst2 = (float*)alloc((size_t)N_ * 4);
    int*       rowptr= (int*)alloc((size_t)(N_ + 1) * 4);
    int*       col   = (int*)alloc((size_t)Etot * 4);
    int2*      pairs = (int2*)alloc((size_t)NPART * pcap * 8);
    int*       pcur  = (int*)alloc((size_t)NPART * 4);

    hipMemsetAsync(pcur, 0, NPART * 4, stream);
    int nTiles = (N_ + 63) / 64;
    int gemm_blocks = min(256, nTiles);
    int per_block = 256 * 8;
    int part_blocks = (Etot + per_block - 1) / per_block;
    gemm1_part_kernel<<<gemm_blocks + part_blocks, 256, 0, stream>>>(
        x, W1, asrc1, adst1, h1h, ssrc1, sdst1, N_, nTiles, gemm_blocks,
        srcp, dstp, E_, Etot, chunk, pairs, pcap, pcur);
    csr_kernel<<<NPART, 512, 0, stream>>>(pairs, pcap, pcur, rowptr, col, N_, chunk, Etot);
    agg1_kernel<<<(N_ + 3) / 4, 256, 0, stream>>>(h1h, ssrc1, sdst1, rowptr, col,
                                                  b1, g1, be1, mu1, var1, hbn1h, N_);
    gemm2_kernel<<<(N_ + 63) / 64, 256, 0, stream>>>(hbn1h, W2, asrc2, adst2, h2h, ssrc2, sdst2, N_);
    agg2_kernel<<<(N_ + 7) / 8, 256, 0, stream>>>(h2h, ssrc2, sdst2, rowptr, col,
                                                  b2, g2, be2, mu2, var2, Wc, bc, (float*)d_out, N_);
}

// Round 17
// 111.720 us; speedup vs baseline: 1.0406x; 1.0406x over previous
//
#include <hip/hip_runtime.h>
#include <hip/hip_fp16.h>

#define NEG 0.2f
#define BNEPS 1e-5f
#define NPART 256

typedef _Float16 f16x8 __attribute__((ext_vector_type(8)));
typedef float f32x4 __attribute__((ext_vector_type(4)));

// ---------------- Fused GEMM1 (MFMA) + edge partition ----------------
__global__ __launch_bounds__(256) void gemm1_part_kernel(
    const float* __restrict__ x, const float* __restrict__ W1,
    const float* __restrict__ asrc, const float* __restrict__ adst,
    __half2* __restrict__ h1h, float* __restrict__ ssrc1, float* __restrict__ sdst1,
    int n, int gemm_blocks,
    const int* __restrict__ srcp, const int* __restrict__ dstp, int E, int Etot, int chunk,
    int2* __restrict__ pairs, int pcap, int* __restrict__ pcur)
{
    __shared__ _Float16 Ws[128 * 136];
    __shared__ _Float16 Xs[4 * 16 * 136];
    int tid = threadIdx.x, lane = tid & 63, wv = tid >> 6;

    if (blockIdx.x >= gemm_blocks) {
        int* lcnt = (int*)Ws;
        int* lbase = (int*)Ws + 256;
        const int PER = 8;
        int t0 = (blockIdx.x - gemm_blocks) * 256 * PER;
        lcnt[tid] = 0;
        __syncthreads();
        int myd[PER], mys[PER], myp[PER];
#pragma unroll
        for (int j = 0; j < PER; ++j) {
            int i = t0 + j * 256 + tid;
            if (i < Etot) {
                int s, d;
                if (i < E) { s = srcp[i]; d = dstp[i]; } else { s = i - E; d = i - E; }
                myd[j] = d; mys[j] = s; myp[j] = d / chunk;
                atomicAdd(&lcnt[myp[j]], 1);
            } else myp[j] = -1;
        }
        __syncthreads();
        lbase[tid] = atomicAdd(&pcur[tid], lcnt[tid]);
        lcnt[tid] = 0;
        __syncthreads();
#pragma unroll
        for (int j = 0; j < PER; ++j) {
            if (myp[j] >= 0) {
                int r = atomicAdd(&lcnt[myp[j]], 1);
                int pos = lbase[myp[j]] + r;
                if (pos < pcap) pairs[(size_t)myp[j] * pcap + pos] = make_int2(myd[j], mys[j]);
            }
        }
        return;
    }

    // ---- gemm1 body ----
#pragma unroll
    for (int it = 0; it < 16; ++it) {
        int idx = it * 256 + tid;          // 128 rows x 32 f4, coalesced
        int c = idx >> 5, kq = idx & 31;
        float4 v = ((const float4*)W1)[idx];
        _Float16* dst = &Ws[c * 136 + kq * 4];
        dst[0] = (_Float16)v.x; dst[1] = (_Float16)v.y;
        dst[2] = (_Float16)v.z; dst[3] = (_Float16)v.w;
    }
    int rbase = blockIdx.x * 64 + wv * 16;
#pragma unroll
    for (int it = 0; it < 8; ++it) {
        int idx = it * 64 + lane;          // 16 rows x 32 f4, coalesced per wave
        int r = idx >> 5, kq = idx & 31;
        int grow = rbase + r;
        float4 v = make_float4(0.f, 0.f, 0.f, 0.f);
        if (grow < n) v = ((const float4*)(x + (size_t)grow * 128))[kq];
        _Float16* dst = &Xs[(wv * 16 + r) * 136 + kq * 4];
        dst[0] = (_Float16)v.x; dst[1] = (_Float16)v.y;
        dst[2] = (_Float16)v.z; dst[3] = (_Float16)v.w;
    }
    __syncthreads();

    int q = lane & 15, kg = lane >> 4;
    f32x4 acc[8];
#pragma unroll
    for (int t = 0; t < 8; ++t) acc[t] = (f32x4){0.f, 0.f, 0.f, 0.f};
#pragma unroll
    for (int kt = 0; kt < 4; ++kt) {
        f16x8 a = *(const f16x8*)&Xs[(wv * 16 + q) * 136 + kt * 32 + kg * 8];
#pragma unroll
        for (int t = 0; t < 8; ++t) {
            f16x8 b = *(const f16x8*)&Ws[(t * 16 + q) * 136 + kt * 32 + kg * 8];
            acc[t] = __builtin_amdgcn_mfma_f32_16x16x32_f16(a, b, acc[t], 0, 0, 0);
        }
    }

    float sp[4][4], sd[4][4];
#pragma unroll
    for (int i = 0; i < 4; ++i)
#pragma unroll
        for (int h = 0; h < 4; ++h) { sp[i][h] = 0.f; sd[i][h] = 0.f; }
#pragma unroll
    for (int t = 0; t < 8; ++t) {
        float as = asrc[t * 16 + q], ad = adst[t * 16 + q];
        int h = t >> 1;
#pragma unroll
        for (int i = 0; i < 4; ++i) {
            sp[i][h] += acc[t][i] * as;
            sd[i][h] += acc[t][i] * ad;
        }
    }
#pragma unroll
    for (int m = 1; m <= 8; m <<= 1) {
#pragma unroll
        for (int i = 0; i < 4; ++i)
#pragma unroll
            for (int h = 0; h < 4; ++h) {
                sp[i][h] += __shfl_xor(sp[i][h], m, 64);
                sd[i][h] += __shfl_xor(sd[i][h], m, 64);
            }
    }
    if (q == 0) {
#pragma unroll
        for (int i = 0; i < 4; ++i) {
            int row = rbase + kg * 4 + i;
            if (row < n) {
#pragma unroll
                for (int h = 0; h < 4; ++h) {
                    ssrc1[row * 4 + h] = sp[i][h];
                    sdst1[row * 4 + h] = sd[i][h];
                }
            }
        }
    }

    __syncthreads();
#pragma unroll
    for (int t = 0; t < 8; ++t)
#pragma unroll
        for (int i = 0; i < 4; ++i)
            Xs[(wv * 16 + kg * 4 + i) * 136 + t * 16 + q] = (_Float16)acc[t][i];
    __syncthreads();
#pragma unroll
    for (int it = 0; it < 4; ++it) {
        int idx = it * 64 + lane;
        int r = idx >> 4, kq = idx & 15;
        int grow = rbase + r;
        if (grow < n)
            ((float4*)((__half*)h1h + (size_t)grow * 128))[kq] =
                *(const float4*)&Xs[(wv * 16 + r) * 136 + kq * 8];
    }
}

// ---------------- CSR pass 2: 512 threads per partition ----------------
__global__ __launch_bounds__(512) void csr_kernel(
    const int2* __restrict__ pairs, int pcap, const int* __restrict__ pcnt,
    int* __restrict__ rowptr, int* __restrict__ col, int N, int chunk, int Etot)
{
    __shared__ int ldeg[NPART];
    __shared__ int wtmp[8];
    __shared__ int sh_pbase;
    int p = blockIdx.x;
    int lo = p * chunk;
    int hi = min(lo + chunk, N);
    int len = max(hi - lo, 0);
    int tid = threadIdx.x;
    int lane = tid & 63, wv = tid >> 6;

    if (tid < NPART) {
        int v = pcnt[tid];
        int inc = v;
#pragma unroll
        for (int m = 1; m < 64; m <<= 1) {
            int t = __shfl_up(inc, m, 64);
            if (lane >= m) inc += t;
        }
        if (lane == 63) wtmp[wv] = inc;
        ldeg[tid] = 0;
        __syncthreads();
        int woff = 0;
        for (int w = 0; w < wv; ++w) woff += wtmp[w];
        if (tid == p) sh_pbase = inc - v + woff;
    } else {
        __syncthreads();
    }
    __syncthreads();

    int cnt = min(pcnt[p], pcap);
    const int2* pp = pairs + (size_t)p * pcap;
    for (int i = tid; i < cnt; i += 512) {
        atomicAdd(&ldeg[pp[i].x - lo], 1);
    }
    __syncthreads();

    int excl = 0;
    if (tid < NPART) {
        int v = (tid < len) ? ldeg[tid] : 0;
        int inc = v;
#pragma unroll
        for (int m = 1; m < 64; m <<= 1) {
            int t = __shfl_up(inc, m, 64);
            if (lane >= m) inc += t;
        }
        if (lane == 63) wtmp[wv] = inc;
        __syncthreads();
        int woff = 0;
        for (int w = 0; w < wv; ++w) woff += wtmp[w];
        excl = inc - v + woff;
    } else {
        __syncthreads();
    }
    int base = sh_pbase;
    __syncthreads();
    if (tid < len) {
        rowptr[lo + tid] = base + excl;
        ldeg[tid] = base + excl;
    }
    if (p == NPART - 1 && tid == 0) rowptr[N] = Etot;
    __syncthreads();

    for (int i = tid; i < cnt; i += 512) {
        int2 e = pp[i];
        int pos = atomicAdd(&ldeg[e.x - lo], 1);
        col[pos] = e.y;
    }
}

// ---------------- GAT layer-1: 4-streams x 16-lane aggregate + bias + BN1 + ELU (fp16 out) -------
__global__ __launch_bounds__(256) void agg1_kernel(
    const __half2* __restrict__ h1h, const float* __restrict__ ssrc1, const float* __restrict__ sdst1,
    const int* __restrict__ rowptr, const int* __restrict__ col,
    const float* __restrict__ b1, const float* __restrict__ g1, const float* __restrict__ be1,
    const float* __restrict__ mu1, const float* __restrict__ var1,
    _Float16* __restrict__ hbn1h, int n)
{
    int node = blockIdx.x * 4 + (threadIdx.x >> 6);
    int lane = threadIdx.x & 63;
    if (node >= n) return;
    int start = rowptr[node], end = rowptr[node + 1];
    int g = lane >> 4;          // edge stream (0..3)
    int q = lane & 15;          // channel quad: ch 8q..8q+7
    int hd = q >> 2;            // head of my 8 channels
    float sdh = sdst1[node * 4 + hd];

    float acc[8] = {0.f, 0.f, 0.f, 0.f, 0.f, 0.f, 0.f, 0.f};
    float dn = 0.f;
#pragma unroll 2
    for (int j = start + g; j < end; j += 4) {
        int s = col[j];
        float e = ssrc1[s * 4 + hd] + sdh;
        e = (e > 0.f) ? e : NEG * e;
        float w = __expf(e);
        dn += w;
        float4 hv = *(const float4*)((const char*)(h1h + (size_t)s * 64) + 16 * q);
        const __half2* hp = (const __half2*)&hv;
#pragma unroll
        for (int t = 0; t < 4; ++t) {
            float2 f = __half22float2(hp[t]);
            acc[2 * t]     += w * f.x;
            acc[2 * t + 1] += w * f.y;
        }
    }
#pragma unroll
    for (int m = 16; m <= 32; m <<= 1) {
        dn += __shfl_xor(dn, m, 64);
#pragma unroll
        for (int t = 0; t < 8; ++t) acc[t] += __shfl_xor(acc[t], m, 64);
    }
    if (lane < 16) {
        float iv = 1.f / dn;
        int c = 8 * q;
        float outv[8];
#pragma unroll
        for (int tt = 0; tt < 2; ++tt) {
            float4 bv = *(const float4*)(b1 + c + 4 * tt);
            float4 gv = *(const float4*)(g1 + c + 4 * tt);
            float4 ev = *(const float4*)(be1 + c + 4 * tt);
            float4 mv = *(const float4*)(mu1 + c + 4 * tt);
            float4 vv = *(const float4*)(var1 + c + 4 * tt);
            const float* bp = (const float*)&bv;
            const float* gp = (const float*)&gv;
            const float* ep = (const float*)&ev;
            const float* mp = (const float*)&mv;
            const float* vp = (const float*)&vv;
#pragma unroll
            for (int t = 0; t < 4; ++t) {
                float u = acc[4 * tt + t] * iv + bp[t];
                u = (u - mp[t]) * (gp[t] * rsqrtf(vp[t] + BNEPS)) + ep[t];
                outv[4 * tt + t] = (u > 0.f) ? u : (__expf(u) - 1.f);
            }
        }
        f16x8 ov;
#pragma unroll
        for (int t = 0; t < 8; ++t) ov[t] = (_Float16)outv[t];
        *(f16x8*)&hbn1h[(size_t)node * 128 + c] = ov;
    }
}

// ---------------- GEMM2 (MFMA): h2 = hbn1 @ W2^T [N,32] fp16 + s_src2/s_dst2 [N] ----------------
__global__ __launch_bounds__(256) void gemm2_kernel(
    const _Float16* __restrict__ hbn1h, const float* __restrict__ W2,
    const float* __restrict__ asrc2, const float* __restrict__ adst2,
    __half2* __restrict__ h2h, float* __restrict__ ssrc2, float* __restrict__ sdst2, int n)
{
    __shared__ _Float16 Ws[32 * 136];
    int tid = threadIdx.x, lane = tid & 63, wv = tid >> 6;
#pragma unroll
    for (int it = 0; it < 4; ++it) {
        int idx = it * 256 + tid;
        int c = idx >> 5, kq = idx & 31;
        float4 v = ((const float4*)W2)[idx];
        _Float16* dst = &Ws[c * 136 + kq * 4];
        dst[0] = (_Float16)v.x; dst[1] = (_Float16)v.y;
        dst[2] = (_Float16)v.z; dst[3] = (_Float16)v.w;
    }
    __syncthreads();

    int rbase = blockIdx.x * 64 + wv * 16;
    int q = lane & 15, kg = lane >> 4;
    int arow = min(rbase + q, n - 1);
    f32x4 acc[2];
    acc[0] = (f32x4){0.f, 0.f, 0.f, 0.f};
    acc[1] = (f32x4){0.f, 0.f, 0.f, 0.f};
#pragma unroll
    for (int kt = 0; kt < 4; ++kt) {
        f16x8 a = *(const f16x8*)&hbn1h[(size_t)arow * 128 + kt * 32 + kg * 8];
#pragma unroll
        for (int t = 0; t < 2; ++t) {
            f16x8 b = *(const f16x8*)&Ws[(t * 16 + q) * 136 + kt * 32 + kg * 8];
            acc[t] = __builtin_amdgcn_mfma_f32_16x16x32_f16(a, b, acc[t], 0, 0, 0);
        }
    }

    float sp[4] = {0.f, 0.f, 0.f, 0.f}, sd[4] = {0.f, 0.f, 0.f, 0.f};
#pragma unroll
    for (int t = 0; t < 2; ++t) {
        float as = asrc2[t * 16 + q], ad = adst2[t * 16 + q];
#pragma unroll
        for (int i = 0; i < 4; ++i) {
            sp[i] += acc[t][i] * as;
            sd[i] += acc[t][i] * ad;
        }
    }
#pragma unroll
    for (int m = 1; m <= 8; m <<= 1) {
#pragma unroll
        for (int i = 0; i < 4; ++i) {
            sp[i] += __shfl_xor(sp[i], m, 64);
            sd[i] += __shfl_xor(sd[i], m, 64);
        }
    }
    if (q == 0) {
#pragma unroll
        for (int i = 0; i < 4; ++i) {
            int row = rbase + kg * 4 + i;
            if (row < n) { ssrc2[row] = sp[i]; sdst2[row] = sd[i]; }
        }
    }
#pragma unroll
    for (int t = 0; t < 2; ++t) {
#pragma unroll
        for (int i = 0; i < 4; ++i) {
            float v = acc[t][i];
            float vn = __shfl_xor(v, 1, 64);
            if ((q & 1) == 0) {
                int row = rbase + kg * 4 + i;
                if (row < n)
                    h2h[(size_t)row * 16 + t * 8 + (q >> 1)] = __floats2half2_rn(v, vn);
            }
        }
    }
}

// ---------------- GAT layer-2: 8-streams x 2 nodes/wave aggregate + BN2 + ELU + classifier -------
__global__ __launch_bounds__(256) void agg2_kernel(
    const __half2* __restrict__ h2h, const float* __restrict__ ssrc2, const float* __restrict__ sdst2,
    const int* __restrict__ rowptr, const int* __restrict__ col,
    const float* __restrict__ b2, const float* __restrict__ g2, const float* __restrict__ be2,
    const float* __restrict__ mu2, const float* __restrict__ var2,
    const float* __restrict__ Wc, const float* __restrict__ bc,
    float* __restrict__ out, int n)
{
    int tid = threadIdx.x;
    int lane = tid & 63;
    int node = blockIdx.x * 8 + (tid >> 6) * 2 + (lane >> 5);
    if (node >= n) return;
    int g = (lane >> 2) & 7;
    int cq = lane & 3;
    int start = rowptr[node], end = rowptr[node + 1];
    float sd = sdst2[node];

    float acc[8] = {0.f, 0.f, 0.f, 0.f, 0.f, 0.f, 0.f, 0.f};
    float dn = 0.f;
    for (int j = start + g; j < end; j += 8) {
        int s = col[j];
        float e = ssrc2[s] + sd;
        e = (e > 0.f) ? e : NEG * e;
        float w = __expf(e);
        dn += w;
        float4 hv = *(const float4*)((const char*)(h2h + (size_t)s * 16) + 16 * cq);
        const __half2* hp = (const __half2*)&hv;
#pragma unroll
        for (int t = 0; t < 4; ++t) {
            float2 f = __half22float2(hp[t]);
            acc[2 * t]     += w * f.x;
            acc[2 * t + 1] += w * f.y;
        }
    }
#pragma unroll
    for (int m = 4; m <= 16; m <<= 1) {
        dn += __shfl_xor(dn, m, 64);
#pragma unroll
        for (int t = 0; t < 8; ++t) acc[t] += __shfl_xor(acc[t], m, 64);
    }
    float iv = 1.f / dn;
    int c = 8 * cq;
    float4 b0 = *(const float4*)(b2 + c),   b4 = *(const float4*)(b2 + c + 4);
    float4 g0 = *(const float4*)(g2 + c),   g4 = *(const float4*)(g2 + c + 4);
    float4 e0 = *(const float4*)(be2 + c),  e4 = *(const float4*)(be2 + c + 4);
    float4 m0 = *(const float4*)(mu2 + c),  m4 = *(const float4*)(mu2 + c + 4);
    float4 v0 = *(const float4*)(var2 + c), v4 = *(const float4*)(var2 + c + 4);
    const float* bp = (const float*)&b0;  const float* bp4 = (const float*)&b4;
    const float* gp = (const float*)&g0;  const float* gp4 = (const float*)&g4;
    const float* ep = (const float*)&e0;  const float* ep4 = (const float*)&e4;
    const float* mp = (const float*)&m0;  const float* mp4 = (const float*)&m4;
    const float* vp = (const float*)&v0;  const float* vp4 = (const float*)&v4;
    float v[8];
#pragma unroll
    for (int t = 0; t < 4; ++t) {
        float u = acc[t] * iv + bp[t];
        u = (u - mp[t]) * (gp[t] * rsqrtf(vp[t] + BNEPS)) + ep[t];
        v[t] = (u > 0.f) ? u : (__expf(u) - 1.f);
    }
#pragma unroll
    for (int t = 0; t < 4; ++t) {
        float u = acc[4 + t] * iv + bp4[t];
        u = (u - mp4[t]) * (gp4[t] * rsqrtf(vp4[t] + BNEPS)) + ep4[t];
        v[4 + t] = (u > 0.f) ? u : (__expf(u) - 1.f);
    }
#pragma unroll
    for (int rr = 0; rr < 2; ++rr) {
        int o = g + 8 * rr;
        float t = 0.f;
        if (o < 10) {
            const float* wc = Wc + o * 32 + c;
#pragma unroll
            for (int k = 0; k < 8; ++k) t += v[k] * wc[k];
        }
        t += __shfl_xor(t, 1, 64);
        t += __shfl_xor(t, 2, 64);
        if (cq == 0 && o < 10) out[(size_t)node * 10 + o] = t + bc[o];
    }
}

extern "C" void kernel_launch(void* const* d_in, const int* in_sizes, int n_in,
                              void* d_out, int out_size, void* d_ws, size_t ws_size,
                              hipStream_t stream)
{
    const float* x     = (const float*)d_in[0];
    const int*   ei    = (const int*)d_in[1];
    const float* W1    = (const float*)d_in[2];
    const float* asrc1 = (const float*)d_in[3];
    const float* adst1 = (const float*)d_in[4];
    const float* b1    = (const float*)d_in[5];
    const float* g1    = (const float*)d_in[6];
    const float* be1   = (const float*)d_in[7];
    const float* mu1   = (const float*)d_in[8];
    const float* var1  = (const float*)d_in[9];
    const float* W2    = (const float*)d_in[10];
    const float* asrc2 = (const float*)d_in[11];
    const float* adst2 = (const float*)d_in[12];
    const float* b2    = (const float*)d_in[13];
    const float* g2    = (const float*)d_in[14];
    const float* be2   = (const float*)d_in[15];
    const float* mu2   = (const float*)d_in[16];
    const float* var2  = (const float*)d_in[17];
    const float* Wc    = (const float*)d_in[18];
    const float* bc    = (const float*)d_in[19];

    int N_ = in_sizes[0] / 128;
    int E_ = in_sizes[1] / 2;
    int Etot = E_ + N_;
    const int* srcp = ei;
    const int* dstp = ei + E_;
    int chunk = (N_ + NPART - 1) / NPART;
    int pcap = Etot / NPART + 1024;

    char* ws = (char*)d_ws;
    size_t off = 0;
    auto alloc = [&](size_t bytes) -> char* {
        char* p = ws + off;
        off += (bytes + 255) & ~(size_t)255;
        return p;
    };
    __half2*   h1h   = (__half2*)alloc((size_t)N_ * 64 * 4);
    _Float16*  hbn1h = (_Float16*)alloc((size_t)N_ * 128 * 2);
    __half2*   h2h   = (__half2*)alloc((size_t)N_ * 16 * 4);
    float*     ssrc1 = (float*)alloc((size_t)N_ * 4 * 4);
    float*     sdst1 = (float*)alloc((size_t)N_ * 4 * 4);
    float*     ssrc2 = (float*)alloc((size_t)N_ * 4);
    float*     sdst2 = (float*)alloc((size_t)N_ * 4);
    int*       rowptr= (int*)alloc((size_t)(N_ + 1) * 4);
    int*       col   = (int*)alloc((size_t)Etot * 4);
    int2*      pairs = (int2*)alloc((size_t)NPART * pcap * 8);
    int*       pcur  = (int*)alloc((size_t)NPART * 4);

    hipMemsetAsync(pcur, 0, NPART * 4, stream);
    int gemm_blocks = (N_ + 63) / 64;
    int per_block = 256 * 8;
    int part_blocks = (Etot + per_block - 1) / per_block;
    gemm1_part_kernel<<<gemm_blocks + part_blocks, 256, 0, stream>>>(
        x, W1, asrc1, adst1, h1h, ssrc1, sdst1, N_, gemm_blocks,
        srcp, dstp, E_, Etot, chunk, pairs, pcap, pcur);
    csr_kernel<<<NPART, 512, 0, stream>>>(pairs, pcap, pcur, rowptr, col, N_, chunk, Etot);
    agg1_kernel<<<(N_ + 3) / 4, 256, 0, stream>>>(h1h, ssrc1, sdst1, rowptr, col,
                                                  b1, g1, be1, mu1, var1, hbn1h, N_);
    gemm2_kernel<<<(N_ + 63) / 64, 256, 0, stream>>>(hbn1h, W2, asrc2, adst2, h2h, ssrc2, sdst2, N_);
    agg2_kernel<<<(N_ + 7) / 8, 256, 0, stream>>>(h2h, ssrc2, sdst2, rowptr, col,
                                                  b2, g2, be2, mu2, var2, Wc, bc, (float*)d_out, N_);
}